// Round 13
// baseline (559.735 us; speedup 1.0000x reference)
//
#include <hip/hip_runtime.h>
#include <cmath>

#define NB 16
#define TAILV 3.0f
#define MINV 0.001f
#define CSC 0.984f   // 1 - NB*MINV
#define PROW 1600    // params row stride (fp16): 32 dims x 50

typedef __attribute__((ext_vector_type(8))) _Float16 half8;
typedef __attribute__((ext_vector_type(4))) float f32x4;

#define MFMA16(a,b,c) __builtin_amdgcn_mfma_f32_16x16x32_f16(a,b,c,0,0,0)

__device__ __forceinline__ ushort f2h(float f) {
    union { _Float16 h; ushort u; } v; v.h = (_Float16)f; return v.u;
}
__device__ __forceinline__ float softplus_f(float x) {
    return (x > 20.0f) ? x : __logf(1.0f + __expf(x));
}

// ---- prologue: coalesced LDS-tiled transpose into d_ws (fp16, [N][K]) ----
// W3T: [1568][256] un-padded. 98 + 16 + 1 = 115 blocks.
__global__ void __launch_bounds__(256)
cvt_weights(const float* __restrict__ W1, const float* __restrict__ W2,
            const float* __restrict__ W3,
            ushort* __restrict__ W3T, ushort* __restrict__ W2T,
            ushort* __restrict__ W1T)
{
    __shared__ ushort sT[16 * 264];
    const int b = blockIdx.x, t = threadIdx.x;

    if (b < 98) {                // ---- W3T ----
        const int n0 = b * 16;
        const int cl = t & 15, kq = t >> 4;
        #pragma unroll
        for (int kb = 0; kb < 16; ++kb) {
            int k = kb * 16 + kq;
            sT[cl * 264 + k] = f2h(W3[(size_t)k * 1568 + n0 + cl]);
        }
        __syncthreads();
        const int r = t >> 4, kc = t & 15;
        #pragma unroll
        for (int j = 0; j < 16; ++j)
            W3T[(size_t)(n0 + r) * 256 + kc * 16 + j] = sT[r * 264 + kc * 16 + j];
    } else if (b < 114) {        // ---- W2T ----
        const int n0 = (b - 98) * 16;
        const int cl = t & 15, kq = t >> 4;
        #pragma unroll
        for (int kb = 0; kb < 16; ++kb) {
            int k = kb * 16 + kq;
            sT[cl * 264 + k] = f2h(W2[(size_t)k * 256 + n0 + cl]);
        }
        __syncthreads();
        const int r = t >> 4, kc = t & 15;
        #pragma unroll
        for (int j = 0; j < 16; ++j)
            W2T[(size_t)(n0 + r) * 256 + kc * 16 + j] = sT[r * 264 + kc * 16 + j];
    } else {                     // ---- W1T ----
        #pragma unroll
        for (int k = 0; k < 32; ++k)
            W1T[t * 32 + k] = f2h(W1[k * 256 + t]);
    }
}

// ---- kernel 1: MLP (3 GEMMs), params -> d_ws fp16 [65536][1600] ----
// 64 rows/block, 1024 blocks. Phase 4 un-padded: 98 tiles split 25/24/25/24
// across waves; fp16 store addr = c + c/49 (50-slot per dim, slot 49 unused).
extern "C" __global__ void __launch_bounds__(256, 2)
rq_gemm(const float* __restrict__ x1,
        const float* __restrict__ b1, const float* __restrict__ b2,
        const float* __restrict__ b3,
        const ushort* __restrict__ W1T, const ushort* __restrict__ W2T,
        const ushort* __restrict__ W3T, ushort* __restrict__ params)
{
    __shared__ char smem[50688];
    ushort* R0  = (ushort*)smem;                   // [32][264] fp16
    ushort* R1  = (ushort*)(smem + 16896);
    ushort* R2  = (ushort*)(smem + 33792);
    ushort* sA1 = R2;                              // [64][40] fp16

    const int tid  = threadIdx.x;
    const int row0 = blockIdx.x * 64;
    const int wave = tid >> 6, lane = tid & 63;
    const int ln = lane & 15, kg = lane >> 4;

    // ---- phase 0: stage x1 (->fp16, R2) ----
    {
        int r = tid >> 2, c = (tid & 3) << 3;
        float4 v0 = *(const float4*)(x1 + (size_t)(row0 + r) * 32 + c);
        float4 v1 = *(const float4*)(x1 + (size_t)(row0 + r) * 32 + c + 4);
        sA1[r*40 + c    ] = f2h(v0.x); sA1[r*40 + c + 1] = f2h(v0.y);
        sA1[r*40 + c + 2] = f2h(v0.z); sA1[r*40 + c + 3] = f2h(v0.w);
        sA1[r*40 + c + 4] = f2h(v1.x); sA1[r*40 + c + 5] = f2h(v1.y);
        sA1[r*40 + c + 6] = f2h(v1.z); sA1[r*40 + c + 7] = f2h(v1.w);
    }
    __syncthreads();

    // ---- phase 1: h1 = relu(x1 @ W1 + b1) ----
    {
        half8 a[4];
        #pragma unroll
        for (int m = 0; m < 4; ++m)
            a[m] = *(const half8*)(sA1 + (m*16 + ln)*40 + kg*8);
        #pragma unroll
        for (int nt = 0; nt < 4; ++nt) {
            int n = wave*64 + nt*16 + ln;
            half8 bfr = *(const half8*)(W1T + n*32 + kg*8);
            float bias = b1[n];
            f32x4 zr = {0.f,0.f,0.f,0.f};
            #pragma unroll
            for (int m = 0; m < 4; ++m) {
                f32x4 cm = MFMA16(a[m], bfr, zr);
                ushort* dst = (m < 2) ? R0 : R1;
                int rb = (m & 1) * 16;
                #pragma unroll
                for (int g = 0; g < 4; ++g)
                    dst[(rb + kg*4 + g)*264 + n] = f2h(fmaxf(cm[g] + bias, 0.f));
            }
        }
    }
    __syncthreads();

    // ---- phase 2: h2 = relu(h1 @ W2 + b2), two half-passes ----
    #pragma unroll
    for (int part = 0; part < 2; ++part) {
        const ushort* S = (part == 0) ? R0 : R1;
        ushort*       D = (part == 0) ? R2 : R0;
        half8 a0[8], a1[8];
        #pragma unroll
        for (int ks = 0; ks < 8; ++ks) {
            a0[ks] = *(const half8*)(S + ln*264 + ks*32 + kg*8);
            a1[ks] = *(const half8*)(S + (16 + ln)*264 + ks*32 + kg*8);
        }
        #pragma unroll
        for (int nt = 0; nt < 4; ++nt) {
            int n = wave*64 + nt*16 + ln;
            f32x4 c0 = {0,0,0,0}, c1 = {0,0,0,0};
            const ushort* bp = W2T + (size_t)n*256 + kg*8;
            #pragma unroll
            for (int ks = 0; ks < 8; ++ks) {
                half8 bfr = *(const half8*)(bp + ks*32);
                c0 = MFMA16(a0[ks], bfr, c0);
                c1 = MFMA16(a1[ks], bfr, c1);
            }
            float bias = b2[n];
            #pragma unroll
            for (int g = 0; g < 4; ++g) {
                D[(kg*4 + g)*264 + n]      = f2h(fmaxf(c0[g] + bias, 0.f));
                D[(16 + kg*4 + g)*264 + n] = f2h(fmaxf(c1[g] + bias, 0.f));
            }
        }
        __syncthreads();
    }

    // ---- phase 3: hoist GEMM3 A-fragments ----
    half8 A[4][8];
    #pragma unroll
    for (int m = 0; m < 4; ++m) {
        const ushort* src = (m < 2) ? R2 : R0;
        int rb = (m & 1) * 16;
        #pragma unroll
        for (int ks = 0; ks < 8; ++ks)
            A[m][ks] = *(const half8*)(src + (rb + ln)*264 + ks*32 + kg*8);
    }

    // ---- phase 4: un-padded GEMM3, fp16 params store ----
    const int ts = (49*wave + 1) >> 1;
    const int te = (49*wave + 50) >> 1;
    half8 bb[2][8];
    {
        const ushort* bp = W3T + (size_t)(ts*16 + ln)*256 + kg*8;
        #pragma unroll
        for (int ks = 0; ks < 8; ++ks) bb[0][ks] = *(const half8*)(bp + ks*32);
    }
    for (int t = ts; t < te; ++t) {
        const int cur = (t - ts) & 1;
        if (t + 1 < te) {
            const ushort* bp = W3T + (size_t)((t+1)*16 + ln)*256 + kg*8;
            #pragma unroll
            for (int ks = 0; ks < 8; ++ks) bb[cur^1][ks] = *(const half8*)(bp + ks*32);
        }
        const int c = t*16 + ln;
        const float bias = b3[c];
        const int dimv = (int)(((unsigned)c * 42800u) >> 21);   // c/49 for c<1568
        ushort* pout = params + (size_t)row0 * PROW + c + dimv;
        f32x4 acc[4];
        #pragma unroll
        for (int m = 0; m < 4; ++m) acc[m] = (f32x4){0,0,0,0};
        #pragma unroll
        for (int ks = 0; ks < 8; ++ks)
            #pragma unroll
            for (int m = 0; m < 4; ++m)
                acc[m] = MFMA16(A[m][ks], bb[cur][ks], acc[m]);
        #pragma unroll
        for (int m = 0; m < 4; ++m)
            #pragma unroll
            for (int g = 0; g < 4; ++g)
                pout[(size_t)(m*16 + kg*4 + g) * PROW] = f2h(acc[m][g] + bias);
    }
}

// ---- kernel 2: spline; 8 rows x 32 dims per block, 8192 blocks ----
extern "C" __global__ void __launch_bounds__(256)
rq_spline(const float* __restrict__ x2, const ushort* __restrict__ params,
          float* __restrict__ zout, float* __restrict__ ldout)
{
    __shared__ ushort sP[8 * PROW];   // 25600 B
    __shared__ float  sLD[8 * 33];

    const int tid = threadIdx.x;
    const size_t base = (size_t)blockIdx.x * 8 * PROW;

    // stage 8 rows of params, coalesced uint4
    {
        const uint4* gp = (const uint4*)(params + base);
        uint4* lp = (uint4*)sP;
        #pragma unroll 2
        for (int i = tid; i < (8 * PROW) / 8; i += 256) lp[i] = gp[i];
    }
    __syncthreads();

    const int row = tid >> 5, dim = tid & 31;
    const int grow = blockIdx.x * 8 + row;
    const _Float16* pp = (const _Float16*)(sP + row * PROW + dim * 50);

    const float x  = x2[(size_t)grow * 32 + dim];
    const float xc = fminf(fmaxf(x, -TAILV), TAILV);

    float e[NB]; float mx = -1e30f;
    #pragma unroll
    for (int k = 0; k < NB; ++k) { e[k] = (float)pp[k]; mx = fmaxf(mx, e[k]); }
    float s = 0.f;
    #pragma unroll
    for (int k = 0; k < NB; ++k) { e[k] = __expf(e[k] - mx); s += e[k]; }
    const float inv = 1.f / s;

    int idx = 0; float xk = -TAILV, xk1 = TAILV, cum = 0.f;
    #pragma unroll
    for (int k = 0; k < NB; ++k) {
        float lo = -TAILV + 2.f * TAILV * cum;
        cum += MINV + CSC * e[k] * inv;
        float hi = -TAILV + 2.f * TAILV * cum;
        if (lo <= xc) { idx = k; xk = lo; xk1 = hi; }
    }

    float eh[NB]; float mh = -1e30f;
    #pragma unroll
    for (int k = 0; k < NB; ++k) { eh[k] = (float)pp[NB + k]; mh = fmaxf(mh, eh[k]); }
    float sh = 0.f;
    #pragma unroll
    for (int k = 0; k < NB; ++k) { eh[k] = __expf(eh[k] - mh); sh += eh[k]; }
    const float invh = 1.f / sh;

    float yk = -TAILV, yk1 = TAILV; cum = 0.f;
    #pragma unroll
    for (int k = 0; k < NB; ++k) {
        float lo = -TAILV + 2.f * TAILV * cum;
        cum += MINV + CSC * eh[k] * invh;
        float hi = -TAILV + 2.f * TAILV * cum;
        if (k == idx) { yk = lo; yk1 = hi; }
    }

    const float d0 = MINV + softplus_f((float)pp[2*NB + idx]);
    const float d1 = MINV + softplus_f((float)pp[2*NB + idx + 1]);

    const float wd = xk1 - xk, hd = yk1 - yk;
    const float sk = hd / wd;
    const float xi = (xc - xk) / wd;
    const float xim = xi * (1.f - xi);
    const float alpha = hd * (sk * xi * xi + d0 * xim);
    const float beta  = sk + (d1 + d0 - 2.f * sk) * xim;
    const float z     = yk + alpha / beta;
    const float om    = 1.f - xi;
    const float dn    = sk * sk * (d1 * xi * xi + 2.f * sk * xim + d0 * om * om);
    const float ld    = __logf(dn) - 2.f * __logf(beta);

    const bool inside = (x >= -TAILV) && (x <= TAILV);
    zout[(size_t)grow * 32 + dim] = inside ? z : x;
    sLD[row * 33 + dim] = inside ? ld : 0.f;
    __syncthreads();

    if (tid < 8) {
        float sld = 0.f;
        #pragma unroll
        for (int j = 0; j < 32; ++j) sld += sLD[tid * 33 + j];
        ldout[blockIdx.x * 8 + tid] = sld;
    }
}

extern "C" void kernel_launch(void* const* d_in, const int* in_sizes, int n_in,
                              void* d_out, int out_size, void* d_ws, size_t ws_size,
                              hipStream_t stream)
{
    const float* x1 = (const float*)d_in[0];
    const float* x2 = (const float*)d_in[1];
    const float* W1 = (const float*)d_in[2];
    const float* b1 = (const float*)d_in[3];
    const float* W2 = (const float*)d_in[4];
    const float* b2 = (const float*)d_in[5];
    const float* W3 = (const float*)d_in[6];
    const float* b3 = (const float*)d_in[7];

    // d_ws layout: params 209.7 MB + weights 0.95 MB  (ws_size = 256 MiB)
    ushort* params = (ushort*)d_ws;                      // [65536][1600] fp16
    ushort* W3T = params + (size_t)65536 * PROW;         // 1568*256 fp16
    ushort* W2T = W3T + 1568 * 256;                      // 256*256 fp16
    ushort* W1T = W2T + 256 * 256;                       // 256*32 fp16

    float* zout  = (float*)d_out;                        // (65536, 32)
    float* ldout = zout + (size_t)65536 * 32;            // (65536,)

    cvt_weights<<<115, 256, 0, stream>>>(W1, W2, W3, W3T, W2T, W1T);
    rq_gemm<<<1024, 256, 0, stream>>>(x1, b1, b2, b3, W1T, W2T, W3T, params);
    rq_spline<<<8192, 256, 0, stream>>>(x2, params, zout, ldout);
}

// Round 15
// 239.289 us; speedup vs baseline: 2.3392x; 2.3392x over previous
//
#include <hip/hip_runtime.h>
#include <cmath>

#define NB 16
#define TAILV 3.0f
#define MINV 0.001f
#define CSC 0.984f   // 1 - NB*MINV

typedef __attribute__((ext_vector_type(8))) _Float16 half8;
typedef __attribute__((ext_vector_type(4))) float f32x4;

#define MFMA16(a,b,c) __builtin_amdgcn_mfma_f32_16x16x32_f16(a,b,c,0,0,0)

__device__ __forceinline__ ushort f2h(float f) {
    union { _Float16 h; ushort u; } v; v.h = (_Float16)f; return v.u;
}
__device__ __forceinline__ float softplus_f(float x) {
    return (x > 20.0f) ? x : __logf(1.0f + __expf(x));
}

// ---- prologue: coalesced LDS-tiled transpose into d_ws (fp16, [N][K]) ----
// W3T: [2048][256], n = dim*64 + p (p<49 real, else 0). Grid = 145.
__global__ void __launch_bounds__(256)
cvt_weights(const float* __restrict__ W1, const float* __restrict__ W2,
            const float* __restrict__ W3, const float* __restrict__ b3,
            ushort* __restrict__ W3T, ushort* __restrict__ W2T,
            ushort* __restrict__ W1T, float* __restrict__ b3p)
{
    __shared__ ushort sT[16 * 264];
    const int b = blockIdx.x, t = threadIdx.x;

    if (b < 128) {               // ---- W3T ----
        const int dim = b >> 2, g = b & 3;
        const int n0 = dim * 64 + g * 16;
        const int cl = t & 15, kq = t >> 4;
        const int p  = g * 16 + cl;
        #pragma unroll
        for (int kb = 0; kb < 16; ++kb) {
            int k = kb * 16 + kq;
            float v = (p < 49) ? W3[(size_t)k * 1568 + dim * 49 + p] : 0.0f;
            sT[cl * 264 + k] = f2h(v);
        }
        if (t < 16) b3p[n0 + t] = (g * 16 + t < 49) ? b3[dim * 49 + g * 16 + t] : 0.0f;
        __syncthreads();
        const int r = t >> 4, kc = t & 15;
        #pragma unroll
        for (int j = 0; j < 16; ++j)
            W3T[(size_t)(n0 + r) * 256 + kc * 16 + j] = sT[r * 264 + kc * 16 + j];
    } else if (b < 144) {        // ---- W2T ----
        const int n0 = (b - 128) * 16;
        const int cl = t & 15, kq = t >> 4;
        #pragma unroll
        for (int kb = 0; kb < 16; ++kb) {
            int k = kb * 16 + kq;
            sT[cl * 264 + k] = f2h(W2[(size_t)k * 256 + n0 + cl]);
        }
        __syncthreads();
        const int r = t >> 4, kc = t & 15;
        #pragma unroll
        for (int j = 0; j < 16; ++j)
            W2T[(size_t)(n0 + r) * 256 + kc * 16 + j] = sT[r * 264 + kc * 16 + j];
    } else {                     // ---- W1T ----
        #pragma unroll
        for (int k = 0; k < 32; ++k)
            W1T[t * 32 + k] = f2h(W1[k * 256 + t]);
    }
}

// ---- fused main kernel: 64 batch rows / block, 4 waves, 1024 blocks ----
// Round-12 structure + LDS diet: myP in fp16 (consistently typed _Float16 on
// BOTH store and load sides — ushort-write/_Float16-read violated TBAA and let
// the compiler hoist spline loads above GEMM stores in barrier-free phase 4).
extern "C" __global__ void __launch_bounds__(256, 2)
rq_mfma(const float* __restrict__ x1, const float* __restrict__ x2,
        const float* __restrict__ b1, const float* __restrict__ b2,
        const ushort* __restrict__ W1T, const ushort* __restrict__ W2T,
        const ushort* __restrict__ W3T, const float* __restrict__ b3p,
        float* __restrict__ zout, float* __restrict__ ldout)
{
    __shared__ char smem[51968];
    float*     sLDw = (float*)smem;                 // [64][5] f32 = 1280
    char*      U    = smem + 1280;                  // 50688-byte union
    ushort*    R0   = (ushort*)U;                   // [32][264] fp16 = 16896
    ushort*    R1   = (ushort*)(U + 16896);         // [32][264]
    ushort*    R2   = (ushort*)(U + 33792);         // [32][264]
    ushort*    sA1  = R2;                           // [64][40] fp16 = 5120
    _Float16*  sPw  = (_Float16*)U;                 // 4 x [64][50] fp16 = 25600 (phase 4)

    const int tid  = threadIdx.x;
    const int row0 = blockIdx.x * 64;
    const int rot  = blockIdx.x & 7;
    const int wave = tid >> 6, lane = tid & 63;
    const int ln = lane & 15, kg = lane >> 4;       // frag: m/n=ln, k-group=kg

    // ---- phase 0: stage x1 (->fp16, R2) ----
    {
        int r = tid >> 2, c = (tid & 3) << 3;
        float4 v0 = *(const float4*)(x1 + (size_t)(row0 + r) * 32 + c);
        float4 v1 = *(const float4*)(x1 + (size_t)(row0 + r) * 32 + c + 4);
        sA1[r*40 + c    ] = f2h(v0.x); sA1[r*40 + c + 1] = f2h(v0.y);
        sA1[r*40 + c + 2] = f2h(v0.z); sA1[r*40 + c + 3] = f2h(v0.w);
        sA1[r*40 + c + 4] = f2h(v1.x); sA1[r*40 + c + 5] = f2h(v1.y);
        sA1[r*40 + c + 6] = f2h(v1.z); sA1[r*40 + c + 7] = f2h(v1.w);
    }
    __syncthreads();

    // ---- phase 1: h1 = relu(x1 @ W1 + b1); 4 M-tiles, K=32 ----
    {
        half8 a[4];
        #pragma unroll
        for (int m = 0; m < 4; ++m)
            a[m] = *(const half8*)(sA1 + (m*16 + ln)*40 + kg*8);
        #pragma unroll
        for (int nt = 0; nt < 4; ++nt) {
            int n = wave*64 + nt*16 + ln;
            half8 bfr = *(const half8*)(W1T + n*32 + kg*8);
            float bias = b1[n];
            f32x4 zr = {0.f,0.f,0.f,0.f};
            #pragma unroll
            for (int m = 0; m < 4; ++m) {
                f32x4 cm = MFMA16(a[m], bfr, zr);
                ushort* dst = (m < 2) ? R0 : R1;
                int rb = (m & 1) * 16;
                #pragma unroll
                for (int g = 0; g < 4; ++g)
                    dst[(rb + kg*4 + g)*264 + n] = f2h(fmaxf(cm[g] + bias, 0.f));
            }
        }
    }
    __syncthreads();

    // ---- phase 2: h2 = relu(h1 @ W2 + b2), two 32-row half-passes ----
    #pragma unroll
    for (int part = 0; part < 2; ++part) {
        const ushort* S = (part == 0) ? R0 : R1;   // h1 rows
        ushort*       D = (part == 0) ? R2 : R0;   // h2 rows
        half8 a0[8], a1[8];
        #pragma unroll
        for (int ks = 0; ks < 8; ++ks) {
            a0[ks] = *(const half8*)(S + ln*264 + ks*32 + kg*8);
            a1[ks] = *(const half8*)(S + (16 + ln)*264 + ks*32 + kg*8);
        }
        #pragma unroll
        for (int nt = 0; nt < 4; ++nt) {
            int n = wave*64 + nt*16 + ln;
            f32x4 c0 = {0,0,0,0}, c1 = {0,0,0,0};
            const ushort* bp = W2T + (size_t)n*256 + kg*8;
            #pragma unroll
            for (int ks = 0; ks < 8; ++ks) {
                half8 bfr = *(const half8*)(bp + ks*32);
                c0 = MFMA16(a0[ks], bfr, c0);
                c1 = MFMA16(a1[ks], bfr, c1);
            }
            float bias = b2[n];
            #pragma unroll
            for (int g = 0; g < 4; ++g) {
                D[(kg*4 + g)*264 + n]      = f2h(fmaxf(c0[g] + bias, 0.f));
                D[(16 + kg*4 + g)*264 + n] = f2h(fmaxf(c1[g] + bias, 0.f));
            }
        }
        __syncthreads();
    }

    // ---- phase 3: hoist GEMM3 A-fragments (4 M-tiles x 8 ks) ----
    half8 A[4][8];
    #pragma unroll
    for (int m = 0; m < 4; ++m) {
        const ushort* src = (m < 2) ? R2 : R0;     // h2 rows 0-31 / 32-63
        int rb = (m & 1) * 16;
        #pragma unroll
        for (int ks = 0; ks < 8; ++ks)
            A[m][ks] = *(const half8*)(src + (rb + ln)*264 + ks*32 + kg*8);
    }
    __syncthreads();   // staging dead; sPw overlays U

    // ---- phase 4: GEMM3 + fused spline; wave owns dims [wave*8, wave*8+8) ----
    _Float16* myP = sPw + wave * (64 * 50);
    float     ldacc = 0.f;

    half8 bcur[8], bnxt[8];
    {
        int dim0 = wave*8 + rot;
        const ushort* bp = W3T + (size_t)(dim0*64 + ln)*256 + kg*8;
        #pragma unroll
        for (int ks = 0; ks < 8; ++ks) bcur[ks] = *(const half8*)(bp + ks*32);
    }

    for (int ch0 = 0; ch0 < 8; ++ch0) {
        const int ch  = (ch0 + rot) & 7;
        const int dim = wave*8 + ch;
        const int nb  = dim * 64;
        float bias[4];
        #pragma unroll
        for (int nt = 0; nt < 4; ++nt) bias[nt] = b3p[nb + nt*16 + ln];

        #pragma unroll
        for (int nt = 0; nt < 4; ++nt) {
            const bool last = (ch0 == 7) && (nt == 3);
            if (!last) {   // prefetch next tile (rotated order)
                int ndim = (nt == 3) ? (wave*8 + ((ch0 + 1 + rot) & 7)) : dim;
                int nnt  = (nt == 3) ? 0 : nt + 1;
                const ushort* bp = W3T + (size_t)(ndim*64 + nnt*16 + ln)*256 + kg*8;
                #pragma unroll
                for (int ks = 0; ks < 8; ++ks) bnxt[ks] = *(const half8*)(bp + ks*32);
            }
            f32x4 c[4];
            #pragma unroll
            for (int m = 0; m < 4; ++m) c[m] = (f32x4){0,0,0,0};
            #pragma unroll
            for (int ks = 0; ks < 8; ++ks)
                #pragma unroll
                for (int m = 0; m < 4; ++m)
                    c[m] = MFMA16(A[m][ks], bcur[ks], c[m]);
            int p = nt*16 + ln;
            if (p < 49) {
                #pragma unroll
                for (int m = 0; m < 4; ++m)
                    #pragma unroll
                    for (int g = 0; g < 4; ++g)
                        myP[(m*16 + kg*4 + g)*50 + p] = (_Float16)(c[m][g] + bias[nt]);
            }
            if (!last) {
                #pragma unroll
                for (int ks = 0; ks < 8; ++ks) bcur[ks] = bnxt[ks];
            }
        }

        // Compiler memory barrier: forbid reordering spline LDS reads above
        // the GEMM LDS stores (no runtime cost; wave-private myP, DS in-order).
        __asm__ __volatile__("" ::: "memory");

        // spline: 64 rows x 1 dim = exactly 1 task/lane (r = lane)
        {
            const _Float16* pp = myP + lane * 50;
            const float x  = x2[(size_t)(row0 + lane) * 32 + dim];
            const float xc = fminf(fmaxf(x, -TAILV), TAILV);

            float e[NB]; float mx = -1e30f;
            #pragma unroll
            for (int k = 0; k < NB; ++k) { e[k] = (float)pp[k]; mx = fmaxf(mx, e[k]); }
            float s = 0.f;
            #pragma unroll
            for (int k = 0; k < NB; ++k) { e[k] = __expf(e[k] - mx); s += e[k]; }
            const float inv = 1.f / s;

            int idx = 0; float xk = -TAILV, xk1 = TAILV, cum = 0.f;
            #pragma unroll
            for (int k = 0; k < NB; ++k) {
                float lo = -TAILV + 2.f * TAILV * cum;
                cum += MINV + CSC * e[k] * inv;
                float hi = -TAILV + 2.f * TAILV * cum;
                if (lo <= xc) { idx = k; xk = lo; xk1 = hi; }
            }

            float eh[NB]; float mh = -1e30f;
            #pragma unroll
            for (int k = 0; k < NB; ++k) { eh[k] = (float)pp[NB + k]; mh = fmaxf(mh, eh[k]); }
            float sh = 0.f;
            #pragma unroll
            for (int k = 0; k < NB; ++k) { eh[k] = __expf(eh[k] - mh); sh += eh[k]; }
            const float invh = 1.f / sh;

            float yk = -TAILV, yk1 = TAILV; cum = 0.f;
            #pragma unroll
            for (int k = 0; k < NB; ++k) {
                float lo = -TAILV + 2.f * TAILV * cum;
                cum += MINV + CSC * eh[k] * invh;
                float hi = -TAILV + 2.f * TAILV * cum;
                if (k == idx) { yk = lo; yk1 = hi; }
            }

            const float d0 = MINV + softplus_f((float)pp[2*NB + idx]);
            const float d1 = MINV + softplus_f((float)pp[2*NB + idx + 1]);

            const float wd = xk1 - xk, hd = yk1 - yk;
            const float sk = hd / wd;
            const float xi = (xc - xk) / wd;
            const float xim = xi * (1.f - xi);
            const float alpha = hd * (sk * xi * xi + d0 * xim);
            const float beta  = sk + (d1 + d0 - 2.f * sk) * xim;
            const float z     = yk + alpha / beta;
            const float om    = 1.f - xi;
            const float dn    = sk * sk * (d1 * xi * xi + 2.f * sk * xim + d0 * om * om);
            const float ld    = __logf(dn) - 2.f * __logf(beta);

            const bool inside = (x >= -TAILV) && (x <= TAILV);
            zout[(size_t)(row0 + lane) * 32 + dim] = inside ? z : x;
            ldacc += inside ? ld : 0.f;
        }
    }
    sLDw[lane*5 + wave] = ldacc;
    __syncthreads();

    // ---- phase 5: log_det reduction across waves ----
    if (tid < 64) {
        float sld = sLDw[tid*5 + 0] + sLDw[tid*5 + 1]
                  + sLDw[tid*5 + 2] + sLDw[tid*5 + 3];
        ldout[row0 + tid] = sld;
    }
}

extern "C" void kernel_launch(void* const* d_in, const int* in_sizes, int n_in,
                              void* d_out, int out_size, void* d_ws, size_t ws_size,
                              hipStream_t stream)
{
    const float* x1 = (const float*)d_in[0];
    const float* x2 = (const float*)d_in[1];
    const float* W1 = (const float*)d_in[2];
    const float* b1 = (const float*)d_in[3];
    const float* W2 = (const float*)d_in[4];
    const float* b2 = (const float*)d_in[5];
    const float* W3 = (const float*)d_in[6];
    const float* b3 = (const float*)d_in[7];

    // d_ws layout (1,204,224 B total)
    ushort* W3T = (ushort*)d_ws;                 // 2048*256 fp16 = 1 MB
    ushort* W2T = W3T + 2048 * 256;              // 256*256 fp16
    ushort* W1T = W2T + 256 * 256;               // 256*32 fp16
    float*  b3p = (float*)(W1T + 256 * 32);      // 2048 f32

    float* zout  = (float*)d_out;                // (65536, 32)
    float* ldout = zout + (size_t)65536 * 32;    // (65536,)

    cvt_weights<<<145, 256, 0, stream>>>(W1, W2, W3, b3, W3T, W2T, W1T, b3p);
    rq_mfma<<<1024, 256, 0, stream>>>(x1, x2, b1, b2, W1T, W2T, W3T, b3p, zout, ldout);
}